// Round 1
// baseline (253.332 us; speedup 1.0000x reference)
//
#include <hip/hip_runtime.h>
#include <math.h>

#define NB 16
#define NA 5
#define NH 96
#define NW 96
#define MAXT 50
#define NC 40
#define CH 45      // 5 + NUM_CLASSES
#define TGT_W 53   // 13 + NUM_CLASSES
#define IGNORE_THRES 0.5f

// anchors / SCALE:  aw = col0, ah = col1
__device__ __constant__ float c_AW[5] = {1.f, 2.f, 4.f, 2.f, 4.f};
__device__ __constant__ float c_AH[5] = {1.f, 2.f, 4.f, 4.f, 2.f};

// ws layout: 10 doubles then 3 ints
//  d[0]=sum_bce0(all cells, tconf=0)   d[1]=cmf_bce correction
//  d[2]=cmf count correction           d[3]=sum mask*bce
//  d[4]=sum mask*ce (cls)              d[5..8]=masked (x,y,w,h) squared err
//  d[9]=nM
//  i[0]=nGT  i[1]=nCorrect  i[2]=nProposals

__device__ __forceinline__ float softplusf(float p) {
    return fmaxf(p, 0.f) + log1pf(expf(-fabsf(p)));
}

__global__ void zero_acc(double* acc, int* iacc) {
    int t = threadIdx.x;
    if (t < 10) acc[t] = 0.0;
    if (t < 3)  iacc[t] = 0;
}

// Dense pass: one thread per cell, reads only channel 0 (conf).
__global__ __launch_bounds__(256) void conf_pass(const float* __restrict__ pred,
                                                 double* acc, int* iacc) {
    int c = blockIdx.x * 256 + threadIdx.x;          // cell index, 737280 total
    float p = pred[(size_t)c * CH];
    float bce = softplusf(p);
    int prop = (p > 0.f) ? 1 : 0;
    // wave(64) reduce
    #pragma unroll
    for (int off = 32; off > 0; off >>= 1) {
        bce  += __shfl_down(bce,  off, 64);
        prop += __shfl_down(prop, off, 64);
    }
    __shared__ float sb[4];
    __shared__ int   sp[4];
    int wid = threadIdx.x >> 6, lane = threadIdx.x & 63;
    if (lane == 0) { sb[wid] = bce; sp[wid] = prop; }
    __syncthreads();
    if (threadIdx.x == 0) {
        atomicAdd(&acc[0], (double)(sb[0] + sb[1] + sb[2] + sb[3]));
        atomicAdd(&iacc[2], sp[0] + sp[1] + sp[2] + sp[3]);
    }
}

// Target pass: one block (one wave) per batch.
__global__ __launch_bounds__(64) void build_targets(const float* __restrict__ pred,
                                                    const float* __restrict__ tgt,
                                                    const int* __restrict__ tsz,
                                                    double* acc, int* iacc) {
    __shared__ int   s_key[MAXT];   // gj*NW+gi, -1 if invalid
    __shared__ int   s_best[MAXT];
    __shared__ int   s_ign[MAXT];   // 5-bit ignore mask (iou > thres)
    __shared__ int   s_lbl[MAXT];
    __shared__ float s_fx[MAXT], s_fy[MAXT], s_gw[MAXT], s_gh[MAXT];

    const int b = blockIdx.x;
    const int t = threadIdx.x;
    const int size_b = tsz[b];
    const bool valid = (t < MAXT) && (t < size_b);
    bool correct = false;

    if (t < MAXT) s_key[t] = -1;

    if (valid) {
        const float* row = tgt + ((size_t)b * MAXT + t) * TGT_W;
        const float inv_s = 1.f / 16.f;
        float gx = row[0] * inv_s, gy = row[1] * inv_s;
        float gh_ = row[3] * inv_s, gw_ = row[4] * inv_s;
        int gi = (int)gx, gj = (int)gy;

        // label = first-max over one-hot
        int lbl = 0; float bv = row[13];
        for (int c = 1; c < NC; ++c) { float v = row[13 + c]; if (v > bv) { bv = v; lbl = c; } }

        // anchor IoUs
        float best_iou = -1e30f; int best = 0; int ign = 0;
        #pragma unroll
        for (int a = 0; a < 5; ++a) {
            float iw = fmaxf(fminf(gw_, c_AW[a]) + 1.f, 0.f);
            float ih = fmaxf(fminf(gh_, c_AH[a]) + 1.f, 0.f);
            float inter = iw * ih;
            float iou = inter / ((gw_ + 1.f) * (gh_ + 1.f) +
                                 (c_AW[a] + 1.f) * (c_AH[a] + 1.f) - inter + 1e-16f);
            if (iou > IGNORE_THRES) ign |= (1 << a);
            if (iou > best_iou) { best_iou = iou; best = a; }   // first-max
        }

        // per-target 'correct' flag (uses prediction at (b,best,gj,gi))
        size_t pbase = ((((size_t)b * NA + best) * NH + gj) * NW + gi) * CH;
        float pc = pred[pbase];
        float px = pred[pbase + 1] + (float)gi;
        float py = pred[pbase + 2] + (float)gj;
        float ph = expf(pred[pbase + 3]) * c_AH[best];
        float pw = expf(pred[pbase + 4]) * c_AW[best];
        float gx1 = gx - gw_ * 0.5f, gx2 = gx + gw_ * 0.5f;
        float gy1 = gy - gh_ * 0.5f, gy2 = gy + gh_ * 0.5f;
        float px1 = px - pw * 0.5f, px2 = px + pw * 0.5f;
        float py1 = py - ph * 0.5f, py2 = py + ph * 0.5f;
        float iw2 = fmaxf(fminf(gx2, px2) - fmaxf(gx1, px1) + 1.f, 0.f);
        float ih2 = fmaxf(fminf(gy2, py2) - fmaxf(gy1, py1) + 1.f, 0.f);
        float inter2 = iw2 * ih2;
        float ga = (gx2 - gx1 + 1.f) * (gy2 - gy1 + 1.f);
        float pa = (px2 - px1 + 1.f) * (py2 - py1 + 1.f);
        float iou2 = inter2 / (ga + pa - inter2 + 1e-16f);
        int pca = 0; float pbv = pred[pbase + 5];
        for (int c = 1; c < NC; ++c) { float v = pred[pbase + 5 + c]; if (v > pbv) { pbv = v; pca = c; } }
        correct = (iou2 > 0.5f) && (pca == lbl) && (pc > 0.5f);

        s_key[t] = gj * NW + gi;
        s_best[t] = best; s_ign[t] = ign; s_lbl[t] = lbl;
        s_fx[t] = gx - (float)gi; s_fy[t] = gy - (float)gj;
        s_gw[t] = gw_; s_gh[t] = gh_;
    }

    unsigned long long vb = __ballot(valid);
    unsigned long long cb = __ballot(correct);
    if (t == 0) {
        atomicAdd(&iacc[0], (int)__popcll(vb));
        atomicAdd(&iacc[1], (int)__popcll(cb));
    }
    __syncthreads();

    // Phase 2: last valid target per cell owns it; replay scan order exactly.
    if (!valid) return;
    const int myKey = s_key[t];
    for (int u = t + 1; u < MAXT; ++u)
        if (s_key[u] == myKey) return;   // not owner

    int cm = 0x1F, m = 0;
    int w[5] = {-1, -1, -1, -1, -1};
    for (int u = 0; u < MAXT; ++u) {
        if (s_key[u] != myKey) continue;
        cm &= ~s_ign[u];                 // set 0 where iou > thres
        int bn = s_best[u];
        cm |= (1 << bn);                 // then force best to 1
        m  |= (1 << bn);
        w[bn] = u;                       // last writer of coords/label
    }

    int gj = myKey / NW, gi = myKey % NW;
    double c_cmf_bce = 0, c_cmf = 0, c_mask_bce = 0, c_cls = 0;
    double c_x = 0, c_y = 0, c_w = 0, c_h = 0, c_nM = 0;
    for (int a = 0; a < 5; ++a) {
        size_t base = ((((size_t)b * NA + a) * NH + gj) * NW + gi) * CH;
        float p = pred[base];
        float s0 = softplusf(p);
        int ma = (m >> a) & 1, cma = (cm >> a) & 1;
        int cmf = (cma != ma) ? 1 : 0;
        // actual cmf*bce(p,tconf=ma) minus default 1*bce(p,0)
        c_cmf_bce += (double)(cmf ? (s0 - p * (float)ma) : 0.f) - (double)s0;
        c_cmf += (double)(cmf - 1);
        if (ma) {
            c_mask_bce += (double)(s0 - p);    // bce with tconf=1
            c_nM += 1.0;
            int u = w[a];
            float x = pred[base + 1], y = pred[base + 2];
            float hh = pred[base + 3], ww = pred[base + 4];
            float tx = s_fx[u], ty = s_fy[u];
            float tw_ = logf(s_gw[u] / c_AW[a] + 1e-16f);
            float th_ = logf(s_gh[u] / c_AH[a] + 1e-16f);
            c_x += (double)((x - tx) * (x - tx));
            c_y += (double)((y - ty) * (y - ty));
            c_w += (double)((ww - tw_) * (ww - tw_));
            c_h += (double)((hh - th_) * (hh - th_));
            // cls CE: logsumexp - cls[lbl]
            float cv[NC];
            float mx = -1e30f;
            for (int c = 0; c < NC; ++c) { cv[c] = pred[base + 5 + c]; mx = fmaxf(mx, cv[c]); }
            float se = 0.f;
            for (int c = 0; c < NC; ++c) se += expf(cv[c] - mx);
            c_cls += (double)(logf(se) + mx - cv[s_lbl[u]]);
        }
    }
    atomicAdd(&acc[1], c_cmf_bce);
    atomicAdd(&acc[2], c_cmf);
    atomicAdd(&acc[3], c_mask_bce);
    atomicAdd(&acc[4], c_cls);
    atomicAdd(&acc[5], c_x);
    atomicAdd(&acc[6], c_y);
    atomicAdd(&acc[7], c_w);
    atomicAdd(&acc[8], c_h);
    atomicAdd(&acc[9], c_nM);
}

__global__ void finalize(const double* acc, const int* iacc, float* out) {
    if (threadIdx.x != 0 || blockIdx.x != 0) return;
    double nM = acc[9];
    double inv_nM = 1.0 / (nM > 0.0 ? nM : 1e-16);
    double lx = acc[5] * inv_nM, ly = acc[6] * inv_nM;
    double lw = acc[7] * inv_nM, lh = acc[8] * inv_nM;
    double l_coord = lx + ly + lw + lh;
    double sum_cmf = (double)(NB * NA * NH * NW) + acc[2];
    double sum_cmf_bce = acc[0] + acc[1];
    double l_conf = sum_cmf_bce / sum_cmf + acc[3] * inv_nM;
    double l_cls = (1.0 / (double)NB) * acc[4] * inv_nM;
    double loss = l_coord + l_conf + l_cls;
    int nGT = iacc[0], nCor = iacc[1], nProp = iacc[2];
    float recall = (float)nCor / (float)(nGT > 1 ? nGT : 1);
    float precision = (nProp > 0) ? ((float)nCor / fmaxf((float)nProp, 1.f)) : 1.f;
    out[0] = (float)loss;
    out[1] = (float)l_coord;
    out[2] = (float)l_conf;
    out[3] = (float)l_cls;
    out[4] = recall;
    out[5] = precision;
}

extern "C" void kernel_launch(void* const* d_in, const int* in_sizes, int n_in,
                              void* d_out, int out_size, void* d_ws, size_t ws_size,
                              hipStream_t stream) {
    const float* pred = (const float*)d_in[0];
    const float* tgt  = (const float*)d_in[1];
    const int*   tsz  = (const int*)d_in[2];
    float* out = (float*)d_out;
    double* acc = (double*)d_ws;
    int* iacc = (int*)((char*)d_ws + 10 * sizeof(double));

    zero_acc<<<1, 32, 0, stream>>>(acc, iacc);
    build_targets<<<NB, 64, 0, stream>>>(pred, tgt, tsz, acc, iacc);
    conf_pass<<<(NB * NA * NH * NW) / 256, 256, 0, stream>>>(pred, acc, iacc);
    finalize<<<1, 64, 0, stream>>>(acc, iacc, out);
}